// Round 4
// baseline (266.459 us; speedup 1.0000x reference)
//
#include <hip/hip_runtime.h>

#define E_DIM 1024
#define D_DIM 128
#define T_DIM 4096

typedef unsigned short u16;
typedef u16 u16x8 __attribute__((ext_vector_type(8)));
typedef u16 u16x4 __attribute__((ext_vector_type(4)));
typedef __bf16 bf16x8 __attribute__((ext_vector_type(8)));
typedef float f32x4 __attribute__((ext_vector_type(4)));

__device__ __forceinline__ u16 cvt_bf16(float f) {
    unsigned u = __float_as_uint(f);
    u += 0x7FFF + ((u >> 16) & 1);   // RNE
    return (u16)(u >> 16);
}

__device__ __forceinline__ float bf2f(u16 v) {
    return __uint_as_float(((unsigned)v) << 16);
}

__device__ __forceinline__ f32x4 mfma16(u16x8 a, u16x8 b, f32x4 c) {
    return __builtin_amdgcn_mfma_f32_16x16x32_bf16(
        __builtin_bit_cast(bf16x8, a), __builtin_bit_cast(bf16x8, b), c, 0, 0, 0);
}

// ---------- prep: transpose weights to [out][in], cast to bf16 ----------
__global__ void prep_kernel(const float* __restrict__ Wk, const float* __restrict__ Wq,
                            const float* __restrict__ Wv, const float* __restrict__ Wp,
                            u16* __restrict__ Wqt, u16* __restrict__ Wkt,
                            u16* __restrict__ Wvt, u16* __restrict__ Wpt) {
    int tid = blockIdx.x * 256 + threadIdx.x;
    const int WT = 128 * 1024;
    if (tid < 3 * WT) {
        int w = tid / WT;
        int r = tid - w * WT;
        int n = r >> 10, k = r & 1023;
        const float* W = (w == 0) ? Wq : (w == 1) ? Wk : Wv;
        u16* Wt = (w == 0) ? Wqt : (w == 1) ? Wkt : Wvt;
        Wt[r] = cvt_bf16(W[k * 128 + n]);
    } else {
        int r = tid - 3 * WT;
        if (r < 128 * 128) {
            int n = r >> 7, k = r & 127;
            Wpt[r] = cvt_bf16(Wp[k * 128 + n]);
        }
    }
}

// ---------- fused QKV projection: x[16384,1024] -> q,k row-major bf16 + v transposed ----------
__global__ __launch_bounds__(256) void qkv_kernel(
        const float* __restrict__ x,
        const u16* __restrict__ Wqt, const u16* __restrict__ Wkt, const u16* __restrict__ Wvt,
        u16* __restrict__ qb, u16* __restrict__ kb, u16* __restrict__ vT) {
    __shared__ u16 Xs[64][40];
    __shared__ u16 Ws[3][128][40];

    const int t = threadIdx.x;
    const int w = t >> 6;
    const int lane = t & 63;
    const int lr = lane & 15;
    const int lg = lane >> 4;
    const int r0 = blockIdx.x * 64;

    f32x4 acc[24];
    #pragma unroll
    for (int i = 0; i < 24; ++i) acc[i] = f32x4{0.f, 0.f, 0.f, 0.f};

    const int xrow = t >> 2;
    const int xseg = t & 3;
    const int wn   = t >> 1;
    const int wh   = (t & 1) * 16;

    const float* xp0 = x + (size_t)(r0 + xrow) * E_DIM + xseg * 8;

    float4 a0 = *(const float4*)(xp0);
    float4 a1 = *(const float4*)(xp0 + 4);
    u16x8 wr[3][2];
    {
        const u16* w0 = Wqt + (size_t)wn * E_DIM + wh;
        const u16* w1 = Wkt + (size_t)wn * E_DIM + wh;
        const u16* w2 = Wvt + (size_t)wn * E_DIM + wh;
        wr[0][0] = *(const u16x8*)w0; wr[0][1] = *(const u16x8*)(w0 + 8);
        wr[1][0] = *(const u16x8*)w1; wr[1][1] = *(const u16x8*)(w1 + 8);
        wr[2][0] = *(const u16x8*)w2; wr[2][1] = *(const u16x8*)(w2 + 8);
    }

    for (int k0 = 0; k0 < E_DIM; k0 += 32) {
        u16x8 xv;
        xv[0] = cvt_bf16(a0.x); xv[1] = cvt_bf16(a0.y);
        xv[2] = cvt_bf16(a0.z); xv[3] = cvt_bf16(a0.w);
        xv[4] = cvt_bf16(a1.x); xv[5] = cvt_bf16(a1.y);
        xv[6] = cvt_bf16(a1.z); xv[7] = cvt_bf16(a1.w);
        *(u16x8*)&Xs[xrow][xseg * 8] = xv;
        #pragma unroll
        for (int j = 0; j < 3; ++j) {
            *(u16x8*)&Ws[j][wn][wh]     = wr[j][0];
            *(u16x8*)&Ws[j][wn][wh + 8] = wr[j][1];
        }
        __syncthreads();

        if (k0 + 32 < E_DIM) {
            const float* xp = xp0 + k0 + 32;
            a0 = *(const float4*)(xp);
            a1 = *(const float4*)(xp + 4);
            const u16* w0 = Wqt + (size_t)wn * E_DIM + k0 + 32 + wh;
            const u16* w1 = Wkt + (size_t)wn * E_DIM + k0 + 32 + wh;
            const u16* w2 = Wvt + (size_t)wn * E_DIM + k0 + 32 + wh;
            wr[0][0] = *(const u16x8*)w0; wr[0][1] = *(const u16x8*)(w0 + 8);
            wr[1][0] = *(const u16x8*)w1; wr[1][1] = *(const u16x8*)(w1 + 8);
            wr[2][0] = *(const u16x8*)w2; wr[2][1] = *(const u16x8*)(w2 + 8);
        }

        u16x8 av = *(u16x8*)&Xs[16 * w + lr][lg * 8];
        #pragma unroll
        for (int nt = 0; nt < 24; ++nt) {
            int j = nt >> 3;
            int n = (nt & 7) * 16 + lr;
            u16x8 bv = *(u16x8*)&Ws[j][n][lg * 8];
            acc[nt] = mfma16(av, bv, acc[nt]);
        }
        __syncthreads();
    }

    const int row0 = r0 + 16 * w + 4 * lg;
    const int bb = row0 >> 12;
    const int tt = row0 & 4095;
    #pragma unroll
    for (int nt = 0; nt < 24; ++nt) {
        int j = nt >> 3;
        int col = (nt & 7) * 16 + lr;
        if (j < 2) {
            u16* outb = (j == 0) ? qb : kb;
            #pragma unroll
            for (int reg = 0; reg < 4; ++reg)
                outb[(size_t)(row0 + reg) * D_DIM + col] = cvt_bf16(acc[nt][reg]);
        } else {
            u16x4 pv;
            #pragma unroll
            for (int reg = 0; reg < 4; ++reg) pv[reg] = cvt_bf16(acc[nt][reg]);
            *(u16x4*)&vT[((size_t)(bb * 128 + col)) * T_DIM + tt] = pv;
        }
    }
}

// ---------- swizzled LDS helpers (32 KB total: Ks 16KB @0, Vt 16KB @16384) ----------
__device__ __forceinline__ void* ksb(char* s, int row, int cb) {
    return s + row * 256 + (cb ^ ((row & 7) << 4));
}
__device__ __forceinline__ void* vtb(char* s, int row, int cb) {
    return s + 16384 + row * 128 + (cb ^ ((row & 7) << 4));
}

// ---------- flash attention (causal), equal-work kv-chunks, bf16 partials ----------
__global__ __launch_bounds__(256, 5) void attn_kernel(
        const u16* __restrict__ qb, const u16* __restrict__ kb, const u16* __restrict__ vT,
        u16* __restrict__ Opart, float* __restrict__ ml, int CT, int LOGCT) {
    // map blockIdx.x = g -> (i, c): band k = i>>LOGCT has CT q-tiles, each with k+1 chunks
    const int g = blockIdx.x;
    int k = 0;
    while ((CT * (k + 1) * (k + 2) / 2) <= g) ++k;
    const int off = g - CT * k * (k + 1) / 2;
    const int iband = off / (k + 1);
    const int c = off - iband * (k + 1);
    const int i = (k << LOGCT) + iband;
    const int b = blockIdx.y;

    const int q0 = i * 64;
    const int kvlen = q0 + 64;
    const int kv_beg = c * CT * 64;
    const int kv_end = min(kvlen, kv_beg + CT * 64);
    const int slot = b * gridDim.x + g;

    __shared__ __align__(16) char smem[32768];

    const int t = threadIdx.x;
    const int w = t >> 6;
    const int lane = t & 63;
    const int lr = lane & 15;
    const int lg = lane >> 4;
    const size_t base = (size_t)b * T_DIM * D_DIM;

    // Q fragments direct from global (L2-resident)
    u16x8 qf[4];
    {
        const u16* qp = qb + base + (size_t)(q0 + 16 * w + lr) * D_DIM + lg * 8;
        #pragma unroll
        for (int dk = 0; dk < 4; ++dk) qf[dk] = *(const u16x8*)(qp + dk * 32);
    }

    const int kr = t >> 2;                // K stage: row 0..63
    const int krb = (t & 3) * 64;         // byte col
    const int vd = t >> 1;                // V stage: row 0..127
    const int vrb = (t & 1) * 64;         // byte col
    const u16* kpb = kb + base;
    const u16* vpb = vT + (size_t)b * D_DIM * T_DIM;

    u16x8 kreg[4], vreg[4];
    #define LOAD_TILE(S0) do {                                                  \
        const u16* kp = kpb + (size_t)((S0) + kr) * D_DIM + (t & 3) * 32;       \
        const u16* vp = vpb + (size_t)vd * T_DIM + (S0) + (t & 1) * 32;         \
        kreg[0] = *(const u16x8*)(kp);      kreg[1] = *(const u16x8*)(kp + 8);  \
        kreg[2] = *(const u16x8*)(kp + 16); kreg[3] = *(const u16x8*)(kp + 24); \
        vreg[0] = *(const u16x8*)(vp);      vreg[1] = *(const u16x8*)(vp + 8);  \
        vreg[2] = *(const u16x8*)(vp + 16); vreg[3] = *(const u16x8*)(vp + 24); \
    } while (0)

    f32x4 oacc[8];
    #pragma unroll
    for (int n = 0; n < 8; ++n) oacc[n] = f32x4{0.f, 0.f, 0.f, 0.f};
    float m_run[4], l_run[4];
    #pragma unroll
    for (int r = 0; r < 4; ++r) { m_run[r] = -1e30f; l_run[r] = 0.f; }
    const float scale2 = 0.12752048520120164f;  // log2(e)/sqrt(128): base-2 softmax

    LOAD_TILE(kv_beg);
    for (int s0 = kv_beg; s0 < kv_end; s0 += 64) {
        // stage K,V (swizzled)
        #pragma unroll
        for (int j = 0; j < 4; ++j) *(u16x8*)ksb(smem, kr, krb + j * 16) = kreg[j];
        #pragma unroll
        for (int j = 0; j < 4; ++j) *(u16x8*)vtb(smem, vd, vrb + j * 16) = vreg[j];
        __syncthreads();                       // sync1: staged
        if (s0 + 64 < kv_end) LOAD_TILE(s0 + 64);   // prefetch under compute

        // S = Q K^T
        f32x4 sacc[4];
        #pragma unroll
        for (int n = 0; n < 4; ++n) sacc[n] = f32x4{0.f, 0.f, 0.f, 0.f};
        __builtin_amdgcn_s_setprio(1);
        #pragma unroll
        for (int dk = 0; dk < 4; ++dk) {
            #pragma unroll
            for (int nt = 0; nt < 4; ++nt) {
                u16x8 bv = *(u16x8*)ksb(smem, nt * 16 + lr, dk * 64 + lg * 16);
                sacc[nt] = mfma16(qf[dk], bv, sacc[nt]);
            }
        }
        __builtin_amdgcn_s_setprio(0);

        float sv[4][4];
        const bool need_mask = (s0 + 63 > q0);
        #pragma unroll
        for (int nt = 0; nt < 4; ++nt) {
            int scol = s0 + nt * 16 + lr;
            #pragma unroll
            for (int r = 0; r < 4; ++r) {
                float v = sacc[nt][r] * scale2;
                if (need_mask && scol > q0 + 16 * w + 4 * lg + r) v = -1e30f;
                sv[nt][r] = v;
            }
        }

        float p[4][4], rsc[4];
        #pragma unroll
        for (int r = 0; r < 4; ++r) {
            float tmax = fmaxf(fmaxf(sv[0][r], sv[1][r]), fmaxf(sv[2][r], sv[3][r]));
            #pragma unroll
            for (int off2 = 1; off2 < 16; off2 <<= 1)
                tmax = fmaxf(tmax, __shfl_xor(tmax, off2));
            float m_new = fmaxf(m_run[r], tmax);
            rsc[r] = __builtin_amdgcn_exp2f(m_run[r] - m_new);
            float tsum = 0.f;
            #pragma unroll
            for (int nt = 0; nt < 4; ++nt) {
                p[nt][r] = __builtin_amdgcn_exp2f(sv[nt][r] - m_new);
                tsum += p[nt][r];
            }
            #pragma unroll
            for (int off2 = 1; off2 < 16; off2 <<= 1)
                tsum += __shfl_xor(tsum, off2);
            l_run[r] = l_run[r] * rsc[r] + tsum;
            m_run[r] = m_new;
        }
        #pragma unroll
        for (int nt = 0; nt < 8; ++nt)
            #pragma unroll
            for (int r = 0; r < 4; ++r) oacc[nt][r] *= rsc[r];

        __syncthreads();                       // sync2: all waves done reading Ks

        // P overwrites Ks region (wave-private rows 16w..16w+15)
        #pragma unroll
        for (int nt = 0; nt < 4; ++nt)
            #pragma unroll
            for (int r = 0; r < 4; ++r)
                *(u16*)ksb(smem, 16 * w + 4 * lg + r, (nt * 16 + lr) * 2) = cvt_bf16(p[nt][r]);

        u16x8 av0 = *(u16x8*)ksb(smem, 16 * w + lr, lg * 16);
        u16x8 av1 = *(u16x8*)ksb(smem, 16 * w + lr, 64 + lg * 16);
        __builtin_amdgcn_s_setprio(1);
        #pragma unroll
        for (int nt = 0; nt < 8; ++nt) {
            u16x8 bv0 = *(u16x8*)vtb(smem, nt * 16 + lr, lg * 16);
            oacc[nt] = mfma16(av0, bv0, oacc[nt]);
            u16x8 bv1 = *(u16x8*)vtb(smem, nt * 16 + lr, 64 + lg * 16);
            oacc[nt] = mfma16(av1, bv1, oacc[nt]);
        }
        __builtin_amdgcn_s_setprio(0);
        __syncthreads();                       // sync3: P & Vt consumed
    }
    #undef LOAD_TILE

    // m,l (base-2) per row
    if (lr == 0) {
        #pragma unroll
        for (int r = 0; r < 4; ++r) {
            int row = 16 * w + 4 * lg + r;
            ml[(size_t)(slot * 64 + row) * 2]     = m_run[r];
            ml[(size_t)(slot * 64 + row) * 2 + 1] = l_run[r];
        }
    }

    // unnormalized O (bf16) -> LDS bounce -> coalesced store
    u16 (*Ob)[128] = reinterpret_cast<u16(*)[128]>(smem);
    #pragma unroll
    for (int nt = 0; nt < 8; ++nt)
        #pragma unroll
        for (int r = 0; r < 4; ++r)
            Ob[16 * w + 4 * lg + r][nt * 16 + lr] = cvt_bf16(oacc[nt][r]);
    __syncthreads();
    u16* op = Opart + (size_t)slot * 8192;
    const int orow = t >> 2, oseg = (t & 3) * 32;
    #pragma unroll
    for (int j = 0; j < 4; ++j)
        *(u16x8*)(op + orow * 128 + oseg + j * 8) = *(u16x8*)&Ob[orow][oseg + j * 8];
}

// ---------- combine partials + fused output projection ----------
__global__ __launch_bounds__(256) void combine_kernel(
        const u16* __restrict__ Opart, const float* __restrict__ ml,
        const u16* __restrict__ Wpt, float* __restrict__ out,
        int CT, int LOGCT, int NSLOT) {
    const int i = blockIdx.x;
    const int b = blockIdx.y;
    const int k = i >> LOGCT;
    const int g0 = CT * k * (k + 1) / 2 + (i & (CT - 1)) * (k + 1);
    const int NC = k + 1;
    const int slot0 = b * NSLOT + g0;

    __shared__ u16 Os[64][136];
    const int t = threadIdx.x;
    const int row = t >> 2, seg = (t & 3) * 32;

    float m_fin = -1e30f;
    for (int c = 0; c < NC; ++c)
        m_fin = fmaxf(m_fin, ml[(size_t)((slot0 + c) * 64 + row) * 2]);

    float acc[32];
    #pragma unroll
    for (int j = 0; j < 32; ++j) acc[j] = 0.f;
    float l_fin = 0.f;
    for (int c = 0; c < NC; ++c) {
        float mcv = ml[(size_t)((slot0 + c) * 64 + row) * 2];
        float lcv = ml[(size_t)((slot0 + c) * 64 + row) * 2 + 1];
        float wgt = __builtin_amdgcn_exp2f(mcv - m_fin);
        l_fin += lcv * wgt;
        const u16* opc = Opart + (size_t)(slot0 + c) * 8192 + row * 128 + seg;
        #pragma unroll
        for (int j = 0; j < 4; ++j) {
            u16x8 v = *(const u16x8*)(opc + j * 8);
            #pragma unroll
            for (int e = 0; e < 8; ++e)
                acc[j * 8 + e] += bf2f(v[e]) * wgt;
        }
    }
    const float inv = 1.f / l_fin;

    #pragma unroll
    for (int j = 0; j < 4; ++j) {
        u16x8 ov;
        #pragma unroll
        for (int e = 0; e < 8; ++e) ov[e] = cvt_bf16(acc[j * 8 + e] * inv);
        *(u16x8*)&Os[row][seg + j * 8] = ov;
    }
    __syncthreads();

    // Y = O @ Wp
    const int w = t >> 6;
    const int lane = t & 63;
    const int lr = lane & 15;
    const int lg = lane >> 4;
    u16x8 af[4];
    #pragma unroll
    for (int dk = 0; dk < 4; ++dk)
        af[dk] = *(u16x8*)&Os[16 * w + lr][dk * 32 + lg * 8];
    float* op = out + ((size_t)b * T_DIM + i * 64) * D_DIM;
    #pragma unroll
    for (int nt = 0; nt < 8; ++nt) {
        f32x4 y = f32x4{0.f, 0.f, 0.f, 0.f};
        #pragma unroll
        for (int dk = 0; dk < 4; ++dk) {
            u16x8 bv = *(const u16x8*)&Wpt[(size_t)(nt * 16 + lr) * D_DIM + dk * 32 + lg * 8];
            y = mfma16(af[dk], bv, y);
        }
        #pragma unroll
        for (int r = 0; r < 4; ++r)
            op[(size_t)(16 * w + 4 * lg + r) * D_DIM + nt * 16 + lr] = y[r];
    }
}

extern "C" void kernel_launch(void* const* d_in, const int* in_sizes, int n_in,
                              void* d_out, int out_size, void* d_ws, size_t ws_size,
                              hipStream_t stream) {
    const float* x  = (const float*)d_in[0];
    const float* Wk = (const float*)d_in[1];
    const float* Wq = (const float*)d_in[2];
    const float* Wv = (const float*)d_in[3];
    const float* Wp = (const float*)d_in[4];
    float* out = (float*)d_out;

    char* ws = (char*)d_ws;
    u16* qb  = (u16*)(ws);                          // 4 MB
    u16* kb  = (u16*)(ws + 4194304);                // 4 MB
    u16* vT  = (u16*)(ws + 8388608);                // 4 MB, [b][d][t]
    u16* Wqt = (u16*)(ws + 12582912);               // 256 KB
    u16* Wkt = (u16*)(ws + 12582912 + 262144);
    u16* Wvt = (u16*)(ws + 12582912 + 524288);
    u16* Wpt = (u16*)(ws + 12582912 + 786432);      // 32 KB
    float* ml   = (float*)(ws + 13631488);          // <= 576 KB
    u16* Opart  = (u16*)(ws + 14680064);            // <= 18.9 MB

    // big path: chunk = 8 kv-tiles (512), equal-work grid of 288 blocks/batch
    const bool big = ws_size >= (size_t)36 * 1024 * 1024;
    const int LOGCT = big ? 3 : 6;
    const int CT = 1 << LOGCT;                      // chunk size in 64-wide tiles
    // grid.x = CT * nb*(nb+1)/2 where nb = 64/CT bands
    const int NB = 64 >> LOGCT;
    const int GX = CT * NB * (NB + 1) / 2;          // 288 (big) or 64 (small)

    prep_kernel<<<1600, 256, 0, stream>>>(Wk, Wq, Wv, Wp, Wqt, Wkt, Wvt, Wpt);
    qkv_kernel<<<256, 256, 0, stream>>>(x, Wqt, Wkt, Wvt, qb, kb, vT);
    attn_kernel<<<dim3(GX, 4), 256, 0, stream>>>(qb, kb, vT, Opart, ml, CT, LOGCT);
    combine_kernel<<<dim3(64, 4), 256, 0, stream>>>(Opart, ml, Wpt, out, CT, LOGCT, GX);
}

// Round 5
// 132.613 us; speedup vs baseline: 2.0093x; 2.0093x over previous
//
#include <hip/hip_runtime.h>

#define E_DIM 1024
#define D_DIM 128
#define T_DIM 4096

typedef unsigned short u16;
typedef u16 u16x8 __attribute__((ext_vector_type(8)));
typedef u16 u16x4 __attribute__((ext_vector_type(4)));
typedef __bf16 bf16x8 __attribute__((ext_vector_type(8)));
typedef float f32x4 __attribute__((ext_vector_type(4)));

__device__ __forceinline__ u16 cvt_bf16(float f) {
    unsigned u = __float_as_uint(f);
    u += 0x7FFF + ((u >> 16) & 1);   // RNE
    return (u16)(u >> 16);
}

__device__ __forceinline__ float bf2f(u16 v) {
    return __uint_as_float(((unsigned)v) << 16);
}

__device__ __forceinline__ f32x4 mfma16(u16x8 a, u16x8 b, f32x4 c) {
    return __builtin_amdgcn_mfma_f32_16x16x32_bf16(
        __builtin_bit_cast(bf16x8, a), __builtin_bit_cast(bf16x8, b), c, 0, 0, 0);
}

// ---------- prep: transpose weights to [out][in], cast to bf16 ----------
__global__ void prep_kernel(const float* __restrict__ Wk, const float* __restrict__ Wq,
                            const float* __restrict__ Wv, const float* __restrict__ Wp,
                            u16* __restrict__ Wqt, u16* __restrict__ Wkt,
                            u16* __restrict__ Wvt, u16* __restrict__ Wpt) {
    int tid = blockIdx.x * 256 + threadIdx.x;
    const int WT = 128 * 1024;
    if (tid < 3 * WT) {
        int w = tid / WT;
        int r = tid - w * WT;
        int n = r >> 10, k = r & 1023;
        const float* W = (w == 0) ? Wq : (w == 1) ? Wk : Wv;
        u16* Wt = (w == 0) ? Wqt : (w == 1) ? Wkt : Wvt;
        Wt[r] = cvt_bf16(W[k * 128 + n]);
    } else {
        int r = tid - 3 * WT;
        if (r < 128 * 128) {
            int n = r >> 7, k = r & 127;
            Wpt[r] = cvt_bf16(Wp[k * 128 + n]);
        }
    }
}

// ---------- fused QKV projection: x[16384,1024] -> q,k row-major bf16 + v transposed ----------
__global__ __launch_bounds__(256) void qkv_kernel(
        const float* __restrict__ x,
        const u16* __restrict__ Wqt, const u16* __restrict__ Wkt, const u16* __restrict__ Wvt,
        u16* __restrict__ qb, u16* __restrict__ kb, u16* __restrict__ vT) {
    __shared__ u16 Xs[64][40];
    __shared__ u16 Ws[3][128][40];

    const int t = threadIdx.x;
    const int w = t >> 6;
    const int lane = t & 63;
    const int lr = lane & 15;
    const int lg = lane >> 4;
    const int r0 = blockIdx.x * 64;

    f32x4 acc[24];
    #pragma unroll
    for (int i = 0; i < 24; ++i) acc[i] = f32x4{0.f, 0.f, 0.f, 0.f};

    const int xrow = t >> 2;
    const int xseg = t & 3;
    const int wn   = t >> 1;
    const int wh   = (t & 1) * 16;

    const float* xp0 = x + (size_t)(r0 + xrow) * E_DIM + xseg * 8;

    float4 a0 = *(const float4*)(xp0);
    float4 a1 = *(const float4*)(xp0 + 4);
    u16x8 wr[3][2];
    {
        const u16* w0 = Wqt + (size_t)wn * E_DIM + wh;
        const u16* w1 = Wkt + (size_t)wn * E_DIM + wh;
        const u16* w2 = Wvt + (size_t)wn * E_DIM + wh;
        wr[0][0] = *(const u16x8*)w0; wr[0][1] = *(const u16x8*)(w0 + 8);
        wr[1][0] = *(const u16x8*)w1; wr[1][1] = *(const u16x8*)(w1 + 8);
        wr[2][0] = *(const u16x8*)w2; wr[2][1] = *(const u16x8*)(w2 + 8);
    }

    for (int k0 = 0; k0 < E_DIM; k0 += 32) {
        u16x8 xv;
        xv[0] = cvt_bf16(a0.x); xv[1] = cvt_bf16(a0.y);
        xv[2] = cvt_bf16(a0.z); xv[3] = cvt_bf16(a0.w);
        xv[4] = cvt_bf16(a1.x); xv[5] = cvt_bf16(a1.y);
        xv[6] = cvt_bf16(a1.z); xv[7] = cvt_bf16(a1.w);
        *(u16x8*)&Xs[xrow][xseg * 8] = xv;
        #pragma unroll
        for (int j = 0; j < 3; ++j) {
            *(u16x8*)&Ws[j][wn][wh]     = wr[j][0];
            *(u16x8*)&Ws[j][wn][wh + 8] = wr[j][1];
        }
        __syncthreads();

        if (k0 + 32 < E_DIM) {
            const float* xp = xp0 + k0 + 32;
            a0 = *(const float4*)(xp);
            a1 = *(const float4*)(xp + 4);
            const u16* w0 = Wqt + (size_t)wn * E_DIM + k0 + 32 + wh;
            const u16* w1 = Wkt + (size_t)wn * E_DIM + k0 + 32 + wh;
            const u16* w2 = Wvt + (size_t)wn * E_DIM + k0 + 32 + wh;
            wr[0][0] = *(const u16x8*)w0; wr[0][1] = *(const u16x8*)(w0 + 8);
            wr[1][0] = *(const u16x8*)w1; wr[1][1] = *(const u16x8*)(w1 + 8);
            wr[2][0] = *(const u16x8*)w2; wr[2][1] = *(const u16x8*)(w2 + 8);
        }

        u16x8 av = *(u16x8*)&Xs[16 * w + lr][lg * 8];
        #pragma unroll
        for (int nt = 0; nt < 24; ++nt) {
            int j = nt >> 3;
            int n = (nt & 7) * 16 + lr;
            u16x8 bv = *(u16x8*)&Ws[j][n][lg * 8];
            acc[nt] = mfma16(av, bv, acc[nt]);
        }
        __syncthreads();
    }

    const int row0 = r0 + 16 * w + 4 * lg;
    const int bb = row0 >> 12;
    const int tt = row0 & 4095;
    #pragma unroll
    for (int nt = 0; nt < 24; ++nt) {
        int j = nt >> 3;
        int col = (nt & 7) * 16 + lr;
        if (j < 2) {
            u16* outb = (j == 0) ? qb : kb;
            #pragma unroll
            for (int reg = 0; reg < 4; ++reg)
                outb[(size_t)(row0 + reg) * D_DIM + col] = cvt_bf16(acc[nt][reg]);
        } else {
            u16x4 pv;
            #pragma unroll
            for (int reg = 0; reg < 4; ++reg) pv[reg] = cvt_bf16(acc[nt][reg]);
            *(u16x4*)&vT[((size_t)(bb * 128 + col)) * T_DIM + tt] = pv;
        }
    }
}

// ---------- swizzled LDS helpers (32 KB total: Ks 16KB @0, Vt 16KB @16384) ----------
__device__ __forceinline__ void* ksb(char* s, int row, int cb) {
    return s + row * 256 + (cb ^ ((row & 7) << 4));
}
__device__ __forceinline__ void* vtb(char* s, int row, int cb) {
    return s + 16384 + row * 128 + (cb ^ ((row & 7) << 4));
}

// ---------- flash attention (causal), equal-work kv-chunks, bf16 partials ----------
__global__ __launch_bounds__(256) void attn_kernel(
        const u16* __restrict__ qb, const u16* __restrict__ kb, const u16* __restrict__ vT,
        u16* __restrict__ Opart, float* __restrict__ ml, int CT, int LOGCT) {
    // map blockIdx.x = g -> (i, c): band k = i>>LOGCT has CT q-tiles, each with k+1 chunks
    const int g = blockIdx.x;
    int k = 0;
    while ((CT * (k + 1) * (k + 2) / 2) <= g) ++k;
    const int off = g - CT * k * (k + 1) / 2;
    const int iband = off / (k + 1);
    const int c = off - iband * (k + 1);
    const int i = (k << LOGCT) + iband;
    const int b = blockIdx.y;

    const int q0 = i * 64;
    const int kvlen = q0 + 64;
    const int kv_beg = c * CT * 64;
    const int kv_end = min(kvlen, kv_beg + CT * 64);
    const int slot = b * gridDim.x + g;

    __shared__ __align__(16) char smem[32768];

    const int t = threadIdx.x;
    const int w = t >> 6;
    const int lane = t & 63;
    const int lr = lane & 15;
    const int lg = lane >> 4;
    const size_t base = (size_t)b * T_DIM * D_DIM;

    // Q fragments direct from global (L2-resident)
    u16x8 qf[4];
    {
        const u16* qp = qb + base + (size_t)(q0 + 16 * w + lr) * D_DIM + lg * 8;
        #pragma unroll
        for (int dk = 0; dk < 4; ++dk) qf[dk] = *(const u16x8*)(qp + dk * 32);
    }

    const int kr = t >> 2;                // K stage: row 0..63
    const int krb = (t & 3) * 64;         // byte col
    const int vd = t >> 1;                // V stage: row 0..127
    const int vrb = (t & 1) * 64;         // byte col
    const u16* kpb = kb + base;
    const u16* vpb = vT + (size_t)b * D_DIM * T_DIM;

    u16x8 kreg[4], vreg[4];
    #define LOAD_TILE(S0) do {                                                  \
        const u16* kp = kpb + (size_t)((S0) + kr) * D_DIM + (t & 3) * 32;       \
        const u16* vp = vpb + (size_t)vd * T_DIM + (S0) + (t & 1) * 32;         \
        kreg[0] = *(const u16x8*)(kp);      kreg[1] = *(const u16x8*)(kp + 8);  \
        kreg[2] = *(const u16x8*)(kp + 16); kreg[3] = *(const u16x8*)(kp + 24); \
        vreg[0] = *(const u16x8*)(vp);      vreg[1] = *(const u16x8*)(vp + 8);  \
        vreg[2] = *(const u16x8*)(vp + 16); vreg[3] = *(const u16x8*)(vp + 24); \
    } while (0)

    f32x4 oacc[8];
    #pragma unroll
    for (int n = 0; n < 8; ++n) oacc[n] = f32x4{0.f, 0.f, 0.f, 0.f};
    float m_run[4], l_run[4];
    #pragma unroll
    for (int r = 0; r < 4; ++r) { m_run[r] = -1e30f; l_run[r] = 0.f; }
    const float scale2 = 0.12752048520120164f;  // log2(e)/sqrt(128): base-2 softmax

    LOAD_TILE(kv_beg);
    for (int s0 = kv_beg; s0 < kv_end; s0 += 64) {
        // stage K,V (swizzled)
        #pragma unroll
        for (int j = 0; j < 4; ++j) *(u16x8*)ksb(smem, kr, krb + j * 16) = kreg[j];
        #pragma unroll
        for (int j = 0; j < 4; ++j) *(u16x8*)vtb(smem, vd, vrb + j * 16) = vreg[j];
        __syncthreads();                       // sync1: staged
        if (s0 + 64 < kv_end) LOAD_TILE(s0 + 64);   // prefetch under compute

        // S = Q K^T
        f32x4 sacc[4];
        #pragma unroll
        for (int n = 0; n < 4; ++n) sacc[n] = f32x4{0.f, 0.f, 0.f, 0.f};
        __builtin_amdgcn_s_setprio(1);
        #pragma unroll
        for (int dk = 0; dk < 4; ++dk) {
            #pragma unroll
            for (int nt = 0; nt < 4; ++nt) {
                u16x8 bv = *(u16x8*)ksb(smem, nt * 16 + lr, dk * 64 + lg * 16);
                sacc[nt] = mfma16(qf[dk], bv, sacc[nt]);
            }
        }
        __builtin_amdgcn_s_setprio(0);

        float sv[4][4];
        const bool need_mask = (s0 + 63 > q0);
        #pragma unroll
        for (int nt = 0; nt < 4; ++nt) {
            int scol = s0 + nt * 16 + lr;
            #pragma unroll
            for (int r = 0; r < 4; ++r) {
                float v = sacc[nt][r] * scale2;
                if (need_mask && scol > q0 + 16 * w + 4 * lg + r) v = -1e30f;
                sv[nt][r] = v;
            }
        }

        float p[4][4], rsc[4];
        #pragma unroll
        for (int r = 0; r < 4; ++r) {
            float tmax = fmaxf(fmaxf(sv[0][r], sv[1][r]), fmaxf(sv[2][r], sv[3][r]));
            #pragma unroll
            for (int off2 = 1; off2 < 16; off2 <<= 1)
                tmax = fmaxf(tmax, __shfl_xor(tmax, off2));
            float m_new = fmaxf(m_run[r], tmax);
            rsc[r] = __builtin_amdgcn_exp2f(m_run[r] - m_new);
            float tsum = 0.f;
            #pragma unroll
            for (int nt = 0; nt < 4; ++nt) {
                p[nt][r] = __builtin_amdgcn_exp2f(sv[nt][r] - m_new);
                tsum += p[nt][r];
            }
            #pragma unroll
            for (int off2 = 1; off2 < 16; off2 <<= 1)
                tsum += __shfl_xor(tsum, off2);
            l_run[r] = l_run[r] * rsc[r] + tsum;
            m_run[r] = m_new;
        }
        #pragma unroll
        for (int nt = 0; nt < 8; ++nt)
            #pragma unroll
            for (int r = 0; r < 4; ++r) oacc[nt][r] *= rsc[r];

        __syncthreads();                       // sync2: all waves done reading Ks

        // P overwrites Ks region (wave-private rows 16w..16w+15)
        #pragma unroll
        for (int nt = 0; nt < 4; ++nt)
            #pragma unroll
            for (int r = 0; r < 4; ++r)
                *(u16*)ksb(smem, 16 * w + 4 * lg + r, (nt * 16 + lr) * 2) = cvt_bf16(p[nt][r]);

        u16x8 av0 = *(u16x8*)ksb(smem, 16 * w + lr, lg * 16);
        u16x8 av1 = *(u16x8*)ksb(smem, 16 * w + lr, 64 + lg * 16);
        __builtin_amdgcn_s_setprio(1);
        #pragma unroll
        for (int nt = 0; nt < 8; ++nt) {
            u16x8 bv0 = *(u16x8*)vtb(smem, nt * 16 + lr, lg * 16);
            oacc[nt] = mfma16(av0, bv0, oacc[nt]);
            u16x8 bv1 = *(u16x8*)vtb(smem, nt * 16 + lr, 64 + lg * 16);
            oacc[nt] = mfma16(av1, bv1, oacc[nt]);
        }
        __builtin_amdgcn_s_setprio(0);
        __syncthreads();                       // sync3: P & Vt consumed
    }
    #undef LOAD_TILE

    // m,l (base-2) per row
    if (lr == 0) {
        #pragma unroll
        for (int r = 0; r < 4; ++r) {
            int row = 16 * w + 4 * lg + r;
            ml[(size_t)(slot * 64 + row) * 2]     = m_run[r];
            ml[(size_t)(slot * 64 + row) * 2 + 1] = l_run[r];
        }
    }

    // unnormalized O (bf16) -> LDS bounce -> coalesced store
    u16 (*Ob)[128] = reinterpret_cast<u16(*)[128]>(smem);
    #pragma unroll
    for (int nt = 0; nt < 8; ++nt)
        #pragma unroll
        for (int r = 0; r < 4; ++r)
            Ob[16 * w + 4 * lg + r][nt * 16 + lr] = cvt_bf16(oacc[nt][r]);
    __syncthreads();
    u16* op = Opart + (size_t)slot * 8192;
    const int orow = t >> 2, oseg = (t & 3) * 32;
    #pragma unroll
    for (int j = 0; j < 4; ++j)
        *(u16x8*)(op + orow * 128 + oseg + j * 8) = *(u16x8*)&Ob[orow][oseg + j * 8];
}

// ---------- combine partials + fused output projection ----------
__global__ __launch_bounds__(256) void combine_kernel(
        const u16* __restrict__ Opart, const float* __restrict__ ml,
        const u16* __restrict__ Wpt, float* __restrict__ out,
        int CT, int LOGCT, int NSLOT) {
    const int i = blockIdx.x;
    const int b = blockIdx.y;
    const int k = i >> LOGCT;
    const int g0 = CT * k * (k + 1) / 2 + (i & (CT - 1)) * (k + 1);
    const int NC = k + 1;
    const int slot0 = b * NSLOT + g0;

    __shared__ u16 Os[64][136];
    const int t = threadIdx.x;
    const int row = t >> 2, seg = (t & 3) * 32;

    float m_fin = -1e30f;
    for (int c = 0; c < NC; ++c)
        m_fin = fmaxf(m_fin, ml[(size_t)((slot0 + c) * 64 + row) * 2]);

    float acc[32];
    #pragma unroll
    for (int j = 0; j < 32; ++j) acc[j] = 0.f;
    float l_fin = 0.f;
    for (int c = 0; c < NC; ++c) {
        float mcv = ml[(size_t)((slot0 + c) * 64 + row) * 2];
        float lcv = ml[(size_t)((slot0 + c) * 64 + row) * 2 + 1];
        float wgt = __builtin_amdgcn_exp2f(mcv - m_fin);
        l_fin += lcv * wgt;
        const u16* opc = Opart + (size_t)(slot0 + c) * 8192 + row * 128 + seg;
        #pragma unroll
        for (int j = 0; j < 4; ++j) {
            u16x8 v = *(const u16x8*)(opc + j * 8);
            #pragma unroll
            for (int e = 0; e < 8; ++e)
                acc[j * 8 + e] += bf2f(v[e]) * wgt;
        }
    }
    const float inv = 1.f / l_fin;

    #pragma unroll
    for (int j = 0; j < 4; ++j) {
        u16x8 ov;
        #pragma unroll
        for (int e = 0; e < 8; ++e) ov[e] = cvt_bf16(acc[j * 8 + e] * inv);
        *(u16x8*)&Os[row][seg + j * 8] = ov;
    }
    __syncthreads();

    // Y = O @ Wp
    const int w = t >> 6;
    const int lane = t & 63;
    const int lr = lane & 15;
    const int lg = lane >> 4;
    u16x8 af[4];
    #pragma unroll
    for (int dk = 0; dk < 4; ++dk)
        af[dk] = *(u16x8*)&Os[16 * w + lr][dk * 32 + lg * 8];
    float* op = out + ((size_t)b * T_DIM + i * 64) * D_DIM;
    #pragma unroll
    for (int nt = 0; nt < 8; ++nt) {
        f32x4 y = f32x4{0.f, 0.f, 0.f, 0.f};
        #pragma unroll
        for (int dk = 0; dk < 4; ++dk) {
            u16x8 bv = *(const u16x8*)&Wpt[(size_t)(nt * 16 + lr) * D_DIM + dk * 32 + lg * 8];
            y = mfma16(af[dk], bv, y);
        }
        #pragma unroll
        for (int r = 0; r < 4; ++r)
            op[(size_t)(16 * w + 4 * lg + r) * D_DIM + nt * 16 + lr] = y[r];
    }
}

extern "C" void kernel_launch(void* const* d_in, const int* in_sizes, int n_in,
                              void* d_out, int out_size, void* d_ws, size_t ws_size,
                              hipStream_t stream) {
    const float* x  = (const float*)d_in[0];
    const float* Wk = (const float*)d_in[1];
    const float* Wq = (const float*)d_in[2];
    const float* Wv = (const float*)d_in[3];
    const float* Wp = (const float*)d_in[4];
    float* out = (float*)d_out;

    char* ws = (char*)d_ws;
    u16* qb  = (u16*)(ws);                          // 4 MB
    u16* kb  = (u16*)(ws + 4194304);                // 4 MB
    u16* vT  = (u16*)(ws + 8388608);                // 4 MB, [b][d][t]
    u16* Wqt = (u16*)(ws + 12582912);               // 256 KB
    u16* Wkt = (u16*)(ws + 12582912 + 262144);
    u16* Wvt = (u16*)(ws + 12582912 + 524288);
    u16* Wpt = (u16*)(ws + 12582912 + 786432);      // 32 KB
    float* ml   = (float*)(ws + 13631488);          // <= 576 KB
    u16* Opart  = (u16*)(ws + 14680064);            // <= 18.9 MB

    // big path: chunk = 8 kv-tiles (512), equal-work grid of 288 blocks/batch
    const bool big = ws_size >= (size_t)36 * 1024 * 1024;
    const int LOGCT = big ? 3 : 6;
    const int CT = 1 << LOGCT;                      // chunk size in 64-wide tiles
    const int NB = 64 >> LOGCT;
    const int GX = CT * NB * (NB + 1) / 2;          // 288 (big) or 64 (small)

    prep_kernel<<<1600, 256, 0, stream>>>(Wk, Wq, Wv, Wp, Wqt, Wkt, Wvt, Wpt);
    qkv_kernel<<<256, 256, 0, stream>>>(x, Wqt, Wkt, Wvt, qb, kb, vT);
    attn_kernel<<<dim3(GX, 4), 256, 0, stream>>>(qb, kb, vT, Opart, ml, CT, LOGCT);
    combine_kernel<<<dim3(64, 4), 256, 0, stream>>>(Opart, ml, Wpt, out, CT, LOGCT, GX);
}

// Round 6
// 120.892 us; speedup vs baseline: 2.2041x; 1.0970x over previous
//
#include <hip/hip_runtime.h>

#define E_DIM 1024
#define D_DIM 128
#define T_DIM 4096

typedef unsigned short u16;
typedef u16 u16x8 __attribute__((ext_vector_type(8)));
typedef u16 u16x4 __attribute__((ext_vector_type(4)));
typedef __bf16 bf16x8 __attribute__((ext_vector_type(8)));
typedef float f32x4 __attribute__((ext_vector_type(4)));

__device__ __forceinline__ u16 cvt_bf16(float f) {
    unsigned u = __float_as_uint(f);
    u += 0x7FFF + ((u >> 16) & 1);   // RNE
    return (u16)(u >> 16);
}

__device__ __forceinline__ float bf2f(u16 v) {
    return __uint_as_float(((unsigned)v) << 16);
}

__device__ __forceinline__ f32x4 mfma16(u16x8 a, u16x8 b, f32x4 c) {
    return __builtin_amdgcn_mfma_f32_16x16x32_bf16(
        __builtin_bit_cast(bf16x8, a), __builtin_bit_cast(bf16x8, b), c, 0, 0, 0);
}

// async global->LDS DMA, 16B per lane; lds ptr must be wave-uniform base
__device__ __forceinline__ void gld_lds16(const void* g, void* l) {
    __builtin_amdgcn_global_load_lds(
        (const __attribute__((address_space(1))) unsigned int*)g,
        (__attribute__((address_space(3))) unsigned int*)l, 16, 0, 0);
}

// ---------- prep: transpose weights to [out][in], cast to bf16 ----------
__global__ void prep_kernel(const float* __restrict__ Wk, const float* __restrict__ Wq,
                            const float* __restrict__ Wv, const float* __restrict__ Wp,
                            u16* __restrict__ Wqt, u16* __restrict__ Wkt,
                            u16* __restrict__ Wvt, u16* __restrict__ Wpt) {
    int tid = blockIdx.x * 256 + threadIdx.x;
    const int WT = 128 * 1024;
    if (tid < 3 * WT) {
        int w = tid / WT;
        int r = tid - w * WT;
        int n = r >> 10, k = r & 1023;
        const float* W = (w == 0) ? Wq : (w == 1) ? Wk : Wv;
        u16* Wt = (w == 0) ? Wqt : (w == 1) ? Wkt : Wvt;
        Wt[r] = cvt_bf16(W[k * 128 + n]);
    } else {
        int r = tid - 3 * WT;
        if (r < 128 * 128) {
            int n = r >> 7, k = r & 127;
            Wpt[r] = cvt_bf16(Wp[k * 128 + n]);
        }
    }
}

// ---------- fused QKV projection: x[16384,1024] -> q,k row-major bf16 + v transposed ----------
__global__ __launch_bounds__(256) void qkv_kernel(
        const float* __restrict__ x,
        const u16* __restrict__ Wqt, const u16* __restrict__ Wkt, const u16* __restrict__ Wvt,
        u16* __restrict__ qb, u16* __restrict__ kb, u16* __restrict__ vT) {
    __shared__ u16 Xs[64][40];
    __shared__ u16 Ws[3][128][40];

    const int t = threadIdx.x;
    const int w = t >> 6;
    const int lane = t & 63;
    const int lr = lane & 15;
    const int lg = lane >> 4;
    const int r0 = blockIdx.x * 64;

    f32x4 acc[24];
    #pragma unroll
    for (int i = 0; i < 24; ++i) acc[i] = f32x4{0.f, 0.f, 0.f, 0.f};

    const int xrow = t >> 2;
    const int xseg = t & 3;
    const int wn   = t >> 1;
    const int wh   = (t & 1) * 16;

    const float* xp0 = x + (size_t)(r0 + xrow) * E_DIM + xseg * 8;

    float4 a0 = *(const float4*)(xp0);
    float4 a1 = *(const float4*)(xp0 + 4);
    u16x8 wr[3][2];
    {
        const u16* w0 = Wqt + (size_t)wn * E_DIM + wh;
        const u16* w1 = Wkt + (size_t)wn * E_DIM + wh;
        const u16* w2 = Wvt + (size_t)wn * E_DIM + wh;
        wr[0][0] = *(const u16x8*)w0; wr[0][1] = *(const u16x8*)(w0 + 8);
        wr[1][0] = *(const u16x8*)w1; wr[1][1] = *(const u16x8*)(w1 + 8);
        wr[2][0] = *(const u16x8*)w2; wr[2][1] = *(const u16x8*)(w2 + 8);
    }

    for (int k0 = 0; k0 < E_DIM; k0 += 32) {
        u16x8 xv;
        xv[0] = cvt_bf16(a0.x); xv[1] = cvt_bf16(a0.y);
        xv[2] = cvt_bf16(a0.z); xv[3] = cvt_bf16(a0.w);
        xv[4] = cvt_bf16(a1.x); xv[5] = cvt_bf16(a1.y);
        xv[6] = cvt_bf16(a1.z); xv[7] = cvt_bf16(a1.w);
        *(u16x8*)&Xs[xrow][xseg * 8] = xv;
        #pragma unroll
        for (int j = 0; j < 3; ++j) {
            *(u16x8*)&Ws[j][wn][wh]     = wr[j][0];
            *(u16x8*)&Ws[j][wn][wh + 8] = wr[j][1];
        }
        __syncthreads();

        if (k0 + 32 < E_DIM) {
            const float* xp = xp0 + k0 + 32;
            a0 = *(const float4*)(xp);
            a1 = *(const float4*)(xp + 4);
            const u16* w0 = Wqt + (size_t)wn * E_DIM + k0 + 32 + wh;
            const u16* w1 = Wkt + (size_t)wn * E_DIM + k0 + 32 + wh;
            const u16* w2 = Wvt + (size_t)wn * E_DIM + k0 + 32 + wh;
            wr[0][0] = *(const u16x8*)w0; wr[0][1] = *(const u16x8*)(w0 + 8);
            wr[1][0] = *(const u16x8*)w1; wr[1][1] = *(const u16x8*)(w1 + 8);
            wr[2][0] = *(const u16x8*)w2; wr[2][1] = *(const u16x8*)(w2 + 8);
        }

        u16x8 av = *(u16x8*)&Xs[16 * w + lr][lg * 8];
        #pragma unroll
        for (int nt = 0; nt < 24; ++nt) {
            int j = nt >> 3;
            int n = (nt & 7) * 16 + lr;
            u16x8 bv = *(u16x8*)&Ws[j][n][lg * 8];
            acc[nt] = mfma16(av, bv, acc[nt]);
        }
        __syncthreads();
    }

    const int row0 = r0 + 16 * w + 4 * lg;
    const int bb = row0 >> 12;
    const int tt = row0 & 4095;
    #pragma unroll
    for (int nt = 0; nt < 24; ++nt) {
        int j = nt >> 3;
        int col = (nt & 7) * 16 + lr;
        if (j < 2) {
            u16* outb = (j == 0) ? qb : kb;
            #pragma unroll
            for (int reg = 0; reg < 4; ++reg)
                outb[(size_t)(row0 + reg) * D_DIM + col] = cvt_bf16(acc[nt][reg]);
        } else {
            u16x4 pv;
            #pragma unroll
            for (int reg = 0; reg < 4; ++reg) pv[reg] = cvt_bf16(acc[nt][reg]);
            *(u16x4*)&vT[((size_t)(bb * 128 + col)) * T_DIM + tt] = pv;
        }
    }
}

// ---------- flash attention (causal), swapped-QK^T, global_load_lds dbuf ----------
// LDS layout (73728 B): Kbuf[2] @0 (each 64x256B, XOR-swizzled),
//                       Vbuf[2] @32768 (each 128x128B, XOR-swizzled),
//                       Ps @65536 (4 waves x 16 x 128B, XOR-swizzled)
__global__ __launch_bounds__(256) void attn_kernel(
        const u16* __restrict__ qb, const u16* __restrict__ kb, const u16* __restrict__ vT,
        u16* __restrict__ Opart, float* __restrict__ ml, int CT, int LOGCT) {
    const int g = blockIdx.x;
    int k = 0;
    while ((CT * (k + 1) * (k + 2) / 2) <= g) ++k;
    const int off = g - CT * k * (k + 1) / 2;
    const int iband = off / (k + 1);
    const int c = off - iband * (k + 1);
    const int i = (k << LOGCT) + iband;
    const int b = blockIdx.y;

    const int q0 = i * 64;
    const int kv_beg = c * CT * 64;
    const int kv_end = min(q0 + 64, kv_beg + CT * 64);
    const int slot = b * gridDim.x + g;

    __shared__ __align__(16) char smem[73728];

    const int t = threadIdx.x;
    const int w = t >> 6;
    const int lane = t & 63;
    const int lr = lane & 15;
    const int lg = lane >> 4;
    const size_t base = (size_t)b * T_DIM * D_DIM;

    // Q fragments direct from global (L2-resident)
    u16x8 qf[4];
    {
        const u16* qp = qb + base + (size_t)(q0 + 16 * w + lr) * D_DIM + lg * 8;
        #pragma unroll
        for (int dk = 0; dk < 4; ++dk) qf[dk] = *(const u16x8*)(qp + dk * 32);
    }

    const char* kpb = (const char*)(kb + base);
    const char* vpb = (const char*)(vT + (size_t)b * D_DIM * T_DIM);
    const int key = (lr & 7) << 4;

    // async stage tile S0 into buffer BUF; source pre-swizzled so linear DMA
    // writes land at swizzled LDS positions
    #define STAGE(S0, BUF) do {                                                   \
        char* kB_ = smem + (BUF) * 16384;                                         \
        char* vB_ = smem + 32768 + (BUF) * 16384;                                 \
        const int wb_ = (t & 192) * 16;                                           \
        _Pragma("unroll")                                                         \
        for (int c2 = 0; c2 < 4; ++c2) {                                          \
            const int krow_ = c2 * 16 + (t >> 4);                                 \
            gld_lds16(kpb + (size_t)((S0) + krow_) * 256 +                        \
                      (((t & 15) * 16) ^ ((krow_ & 7) * 16)),                     \
                      kB_ + c2 * 4096 + wb_);                                     \
            const int vrow_ = c2 * 32 + (t >> 3);                                 \
            gld_lds16(vpb + (size_t)vrow_ * (T_DIM * 2) + (size_t)(S0) * 2 +      \
                      (((t & 7) * 16) ^ ((vrow_ & 7) * 16)),                      \
                      vB_ + c2 * 4096 + wb_);                                     \
        }                                                                         \
    } while (0)

    f32x4 oacc[8];
    #pragma unroll
    for (int n = 0; n < 8; ++n) oacc[n] = f32x4{0.f, 0.f, 0.f, 0.f};
    float m_run = -1e30f, l_run = 0.f;
    const float scale2 = 0.12752048520120164f;  // log2(e)/sqrt(128)
    const int qrow = q0 + 16 * w + lr;          // this lane's q row (swapped layout)

    STAGE(kv_beg, 0);
    asm volatile("s_waitcnt vmcnt(0)" ::: "memory");
    __syncthreads();

    int buf = 0;
    for (int s0 = kv_beg; s0 < kv_end; s0 += 64) {
        if (s0 + 64 < kv_end) STAGE(s0 + 64, buf ^ 1);   // async prefetch

        char* kB = smem + buf * 16384;
        char* vB = smem + 32768 + buf * 16384;
        char* psB = smem + 65536 + w * 2048;

        // S^T = K Q^T : lane holds S[q=qrow][s=s0+16nt+4lg+r]
        f32x4 sacc[4];
        #pragma unroll
        for (int n = 0; n < 4; ++n) sacc[n] = f32x4{0.f, 0.f, 0.f, 0.f};
        __builtin_amdgcn_s_setprio(1);
        #pragma unroll
        for (int dk = 0; dk < 4; ++dk) {
            #pragma unroll
            for (int nt = 0; nt < 4; ++nt) {
                u16x8 kfr = *(u16x8*)(kB + (nt * 16 + lr) * 256 + ((dk * 64 + lg * 16) ^ key));
                sacc[nt] = mfma16(kfr, qf[dk], sacc[nt]);
            }
        }
        __builtin_amdgcn_s_setprio(0);

        // scale + causal mask (per-lane scalar row)
        float sv[4][4];
        const bool need_mask = (s0 + 63 > q0);
        #pragma unroll
        for (int nt = 0; nt < 4; ++nt) {
            #pragma unroll
            for (int r = 0; r < 4; ++r) {
                float v = sacc[nt][r] * scale2;
                if (need_mask && (s0 + nt * 16 + 4 * lg + r) > qrow) v = -1e30f;
                sv[nt][r] = v;
            }
        }

        // softmax: in-register over 16 + 2-level cross-lg reduce
        float tmax = sv[0][0];
        #pragma unroll
        for (int nt = 0; nt < 4; ++nt)
            #pragma unroll
            for (int r = 0; r < 4; ++r) tmax = fmaxf(tmax, sv[nt][r]);
        tmax = fmaxf(tmax, __shfl_xor(tmax, 16));
        tmax = fmaxf(tmax, __shfl_xor(tmax, 32));
        float m_new = fmaxf(m_run, tmax);
        float rsc = __builtin_amdgcn_exp2f(m_run - m_new);
        m_run = m_new;
        float tsum = 0.f;
        #pragma unroll
        for (int nt = 0; nt < 4; ++nt)
            #pragma unroll
            for (int r = 0; r < 4; ++r) {
                sv[nt][r] = __builtin_amdgcn_exp2f(sv[nt][r] - m_new);
                tsum += sv[nt][r];
            }
        tsum += __shfl_xor(tsum, 16);
        tsum += __shfl_xor(tsum, 32);
        l_run = l_run * rsc + tsum;

        // fetch rsc for oacc rows q'=4lg+r (uniform across lg on lane lr=q')
        float rscq[4];
        #pragma unroll
        for (int r = 0; r < 4; ++r)
            rscq[r] = __shfl(rsc, (lane & 48) | (((lane >> 4) & 3) * 4 + r), 64);
        #pragma unroll
        for (int nt = 0; nt < 8; ++nt)
            #pragma unroll
            for (int r = 0; r < 4; ++r) oacc[nt][r] *= rscq[r];

        // P -> wave-private swizzled Ps: lane writes row q=lr, cols 16nt+4lg+{0..3}
        #pragma unroll
        for (int nt = 0; nt < 4; ++nt) {
            u16x4 pv4;
            #pragma unroll
            for (int r = 0; r < 4; ++r) pv4[r] = cvt_bf16(sv[nt][r]);
            *(u16x4*)(psB + lr * 128 + ((nt * 32 + lg * 8) ^ key)) = pv4;
        }

        // O += P V
        u16x8 av0 = *(u16x8*)(psB + lr * 128 + ((lg * 16) ^ key));
        u16x8 av1 = *(u16x8*)(psB + lr * 128 + ((64 + lg * 16) ^ key));
        __builtin_amdgcn_s_setprio(1);
        #pragma unroll
        for (int nt = 0; nt < 8; ++nt) {
            u16x8 bv0 = *(u16x8*)(vB + (nt * 16 + lr) * 128 + ((lg * 16) ^ key));
            oacc[nt] = mfma16(av0, bv0, oacc[nt]);
            u16x8 bv1 = *(u16x8*)(vB + (nt * 16 + lr) * 128 + ((64 + lg * 16) ^ key));
            oacc[nt] = mfma16(av1, bv1, oacc[nt]);
        }
        __builtin_amdgcn_s_setprio(0);

        asm volatile("s_waitcnt vmcnt(0)" ::: "memory");   // drain prefetch
        __syncthreads();                                   // single barrier per iter
        buf ^= 1;
    }
    #undef STAGE

    // m,l per q row (lane lr owns q=16w+lr; uniform across lg)
    if (lg == 0) {
        int row = 16 * w + lr;
        ml[(size_t)(slot * 64 + row) * 2]     = m_run;
        ml[(size_t)(slot * 64 + row) * 2 + 1] = l_run;
    }

    // normalization factors for oacc rows q'=4lg+r
    float invl = 1.f / l_run;
    float invq[4];
    #pragma unroll
    for (int r = 0; r < 4; ++r)
        invq[r] = __shfl(invl, (lane & 48) | (((lane >> 4) & 3) * 4 + r), 64);

    // unnormalized O (bf16) -> LDS bounce -> coalesced store
    u16 (*Ob)[128] = reinterpret_cast<u16(*)[128]>(smem);
    #pragma unroll
    for (int nt = 0; nt < 8; ++nt)
        #pragma unroll
        for (int r = 0; r < 4; ++r)
            Ob[16 * w + 4 * lg + r][nt * 16 + lr] = cvt_bf16(oacc[nt][r] * invq[r]);
    __syncthreads();
    u16* op = Opart + (size_t)slot * 8192;
    const int orow = t >> 2, oseg = (t & 3) * 32;
    #pragma unroll
    for (int j = 0; j < 4; ++j)
        *(u16x8*)(op + orow * 128 + oseg + j * 8) = *(u16x8*)&Ob[orow][oseg + j * 8];
}

// ---------- combine partials + fused output projection ----------
// NOTE: attn now stores NORMALIZED partials (divided by per-chunk l), so
// combine weights are wgt = exp2(m_c - m_fin) * l_c / l_fin.
__global__ __launch_bounds__(256) void combine_kernel(
        const u16* __restrict__ Opart, const float* __restrict__ ml,
        const u16* __restrict__ Wpt, float* __restrict__ out,
        int CT, int LOGCT, int NSLOT) {
    const int i = blockIdx.x;
    const int b = blockIdx.y;
    const int k = i >> LOGCT;
    const int g0 = CT * k * (k + 1) / 2 + (i & (CT - 1)) * (k + 1);
    const int NC = k + 1;
    const int slot0 = b * NSLOT + g0;

    __shared__ u16 Os[64][136];
    const int t = threadIdx.x;
    const int row = t >> 2, seg = (t & 3) * 32;

    float m_fin = -1e30f;
    for (int c = 0; c < NC; ++c)
        m_fin = fmaxf(m_fin, ml[(size_t)((slot0 + c) * 64 + row) * 2]);

    float acc[32];
    #pragma unroll
    for (int j = 0; j < 32; ++j) acc[j] = 0.f;
    float l_fin = 0.f;
    for (int c = 0; c < NC; ++c) {
        float mcv = ml[(size_t)((slot0 + c) * 64 + row) * 2];
        float lcv = ml[(size_t)((slot0 + c) * 64 + row) * 2 + 1];
        float wgt = __builtin_amdgcn_exp2f(mcv - m_fin) * lcv;
        l_fin += wgt;
        const u16* opc = Opart + (size_t)(slot0 + c) * 8192 + row * 128 + seg;
        #pragma unroll
        for (int j = 0; j < 4; ++j) {
            u16x8 v = *(const u16x8*)(opc + j * 8);
            #pragma unroll
            for (int e = 0; e < 8; ++e)
                acc[j * 8 + e] += bf2f(v[e]) * wgt;
        }
    }
    const float inv = 1.f / l_fin;

    #pragma unroll
    for (int j = 0; j < 4; ++j) {
        u16x8 ov;
        #pragma unroll
        for (int e = 0; e < 8; ++e) ov[e] = cvt_bf16(acc[j * 8 + e] * inv);
        *(u16x8*)&Os[row][seg + j * 8] = ov;
    }
    __syncthreads();

    // Y = O @ Wp
    const int w = t >> 6;
    const int lane = t & 63;
    const int lr = lane & 15;
    const int lg = lane >> 4;
    u16x8 af[4];
    #pragma unroll
    for (int dk = 0; dk < 4; ++dk)
        af[dk] = *(u16x8*)&Os[16 * w + lr][dk * 32 + lg * 8];
    float* op = out + ((size_t)b * T_DIM + i * 64) * D_DIM;
    #pragma unroll
    for (int nt = 0; nt < 8; ++nt) {
        f32x4 y = f32x4{0.f, 0.f, 0.f, 0.f};
        #pragma unroll
        for (int dk = 0; dk < 4; ++dk) {
            u16x8 bv = *(const u16x8*)&Wpt[(size_t)(nt * 16 + lr) * D_DIM + dk * 32 + lg * 8];
            y = mfma16(af[dk], bv, y);
        }
        #pragma unroll
        for (int r = 0; r < 4; ++r)
            op[(size_t)(16 * w + 4 * lg + r) * D_DIM + nt * 16 + lr] = y[r];
    }
}

extern "C" void kernel_launch(void* const* d_in, const int* in_sizes, int n_in,
                              void* d_out, int out_size, void* d_ws, size_t ws_size,
                              hipStream_t stream) {
    const float* x  = (const float*)d_in[0];
    const float* Wk = (const float*)d_in[1];
    const float* Wq = (const float*)d_in[2];
    const float* Wv = (const float*)d_in[3];
    const float* Wp = (const float*)d_in[4];
    float* out = (float*)d_out;

    char* ws = (char*)d_ws;
    u16* qb  = (u16*)(ws);                          // 4 MB
    u16* kb  = (u16*)(ws + 4194304);                // 4 MB
    u16* vT  = (u16*)(ws + 8388608);                // 4 MB, [b][d][t]
    u16* Wqt = (u16*)(ws + 12582912);               // 256 KB
    u16* Wkt = (u16*)(ws + 12582912 + 262144);
    u16* Wvt = (u16*)(ws + 12582912 + 524288);
    u16* Wpt = (u16*)(ws + 12582912 + 786432);      // 32 KB
    float* ml   = (float*)(ws + 13631488);          // <= 576 KB
    u16* Opart  = (u16*)(ws + 14680064);            // <= 18.9 MB

    const bool big = ws_size >= (size_t)36 * 1024 * 1024;
    const int LOGCT = big ? 3 : 6;
    const int CT = 1 << LOGCT;
    const int NB = 64 >> LOGCT;
    const int GX = CT * NB * (NB + 1) / 2;          // 288 (big) or 64 (small)

    prep_kernel<<<1600, 256, 0, stream>>>(Wk, Wq, Wv, Wp, Wqt, Wkt, Wvt, Wpt);
    qkv_kernel<<<256, 256, 0, stream>>>(x, Wqt, Wkt, Wvt, qb, kb, vT);
    attn_kernel<<<dim3(GX, 4), 256, 0, stream>>>(qb, kb, vT, Opart, ml, CT, LOGCT);
    combine_kernel<<<dim3(64, 4), 256, 0, stream>>>(Opart, ml, Wpt, out, CT, LOGCT, GX);
}